// Round 4
// baseline (502.990 us; speedup 1.0000x reference)
//
#include <hip/hip_runtime.h>
#include <hip/hip_bf16.h>
#include <cstdint>

typedef __bf16 v8bf __attribute__((ext_vector_type(8)));
typedef float  v4f  __attribute__((ext_vector_type(4)));

__device__ __forceinline__ unsigned short b16(float f) {
  union { float f; unsigned u; } v; v.f = f;
  unsigned u = v.u;
  return (unsigned short)((u + 0x7fffu + ((u >> 16) & 1u)) >> 16);
}
__device__ __forceinline__ float bf2f(unsigned short u) {
  union { unsigned u; float f; } v; v.u = ((unsigned)u) << 16; return v.f;
}

#define GLOAD_LDS16(g, l)                                                     \
  __builtin_amdgcn_global_load_lds(                                           \
      (const __attribute__((address_space(1))) void*)(g),                     \
      (__attribute__((address_space(3))) void*)(l), 16, 0, 0)

// ---------------- elementwise fp32 -> bf16 convert (x) ----------------
__global__ __launch_bounds__(256) void conv_bf16(const float* __restrict__ in,
                                                 unsigned short* __restrict__ out) {
  size_t idx = (size_t)blockIdx.x * 256 + threadIdx.x;   // one thread = 4 elems
  v4f v = *(const v4f*)(in + idx * 4);
  unsigned long long p = (unsigned long long)b16(v[0]) |
                         ((unsigned long long)b16(v[1]) << 16) |
                         ((unsigned long long)b16(v[2]) << 32) |
                         ((unsigned long long)b16(v[3]) << 48);
  *(unsigned long long*)(out + idx * 4) = p;
}

// ---------------- weight transpose: in[R][C] fp32 -> out[c*R + r] bf16 ----------------
__global__ void transpose_w(const float* __restrict__ in, unsigned short* __restrict__ out,
                            int C, int R) {
  __shared__ float tile[32][33];
  int c0 = blockIdx.x * 32, r0 = blockIdx.y * 32;
  int x = threadIdx.x, y = threadIdx.y;
#pragma unroll
  for (int i = 0; i < 4; ++i)
    tile[y + 8 * i][x] = in[(size_t)(r0 + y + 8 * i) * C + c0 + x];
  __syncthreads();
#pragma unroll
  for (int i = 0; i < 4; ++i)
    out[(size_t)(c0 + y + 8 * i) * R + r0 + x] = b16(tile[x][y + 8 * i]);
}

// ---------------- V transpose: T3[row][1024 + h*128 + d] (bf16) -> VT[bh][d][s] bf16 ----------------
__global__ void transpose_v(const unsigned short* __restrict__ T3, unsigned short* __restrict__ VT) {
  __shared__ unsigned short tile[32][34];
  int bh = blockIdx.z;
  int s0 = blockIdx.x * 32, d0 = blockIdx.y * 32;
  int x = threadIdx.x, y = threadIdx.y;
  const unsigned short* src = T3 + (size_t)(bh >> 4) * 2048 * 3072 + 1024 + (bh & 15) * 128;
#pragma unroll
  for (int i = 0; i < 4; ++i)
    tile[y + 8 * i][x] = src[(size_t)(s0 + y + 8 * i) * 3072 + d0 + x];
  __syncthreads();
  unsigned short* dst = VT + (size_t)bh * 128 * 2048;
#pragma unroll
  for (int i = 0; i < 4; ++i)
    dst[(size_t)(d0 + y + 8 * i) * 2048 + s0 + x] = tile[x][y + 8 * i];
}

// ---------------- GEMM: C[M,N] = A[M,K](bf16) * BT[N,K](bf16) ----------------
// m97 recipe: 128x128 tile, BK=32, 4 waves (2x2), global_load_lds width=16
// into LINEAR [128][32] LDS (wave-uniform base + lane*16 — no padding allowed).
template <bool OUT_BF16>
__global__ __launch_bounds__(256) void gemm_bt(const unsigned short* __restrict__ A,
                                               const unsigned short* __restrict__ BT,
                                               void* __restrict__ Cout,
                                               const float* __restrict__ bias,
                                               int M, int N, int K) {
  __shared__ unsigned short As[128 * 32];
  __shared__ unsigned short Bs[128 * 32];
  const int tid = threadIdx.x;
  const int w = tid >> 6, l = tid & 63;
  const int wm = w >> 1, wn = w & 1;
  const int lg = l >> 4, lr = l & 15;
  const int m0 = blockIdx.y * 128, n0 = blockIdx.x * 128;

  // staging map: call i covers tile rows i*64 + tid/4, k-chunk (tid&3)*8
  const int srow = tid >> 2, scol = (tid & 3) * 8;
  const unsigned short* Ap0 = A  + (size_t)(m0 + srow) * K + scol;
  const unsigned short* Ap1 = A  + (size_t)(m0 + 64 + srow) * K + scol;
  const unsigned short* Bp0 = BT + (size_t)(n0 + srow) * K + scol;
  const unsigned short* Bp1 = BT + (size_t)(n0 + 64 + srow) * K + scol;
  unsigned short* Ad0 = As + tid * 8;          // byte tid*16
  unsigned short* Ad1 = As + 2048 + tid * 8;   // byte 4096 + tid*16
  unsigned short* Bd0 = Bs + tid * 8;
  unsigned short* Bd1 = Bs + 2048 + tid * 8;

  v4f acc[4][4];
#pragma unroll
  for (int i = 0; i < 4; ++i)
#pragma unroll
    for (int j = 0; j < 4; ++j) acc[i][j] = (v4f){0.f, 0.f, 0.f, 0.f};

  for (int k0 = 0; k0 < K; k0 += 32) {
    GLOAD_LDS16(Ap0 + k0, Ad0);
    GLOAD_LDS16(Ap1 + k0, Ad1);
    GLOAD_LDS16(Bp0 + k0, Bd0);
    GLOAD_LDS16(Bp1 + k0, Bd1);
    __syncthreads();
    v8bf af[4], bfr[4];
#pragma unroll
    for (int mi = 0; mi < 4; ++mi)
      af[mi] = *(const v8bf*)&As[(wm * 64 + mi * 16 + lr) * 32 + lg * 8];
#pragma unroll
    for (int ni = 0; ni < 4; ++ni)
      bfr[ni] = *(const v8bf*)&Bs[(wn * 64 + ni * 16 + lr) * 32 + lg * 8];
#pragma unroll
    for (int mi = 0; mi < 4; ++mi)
#pragma unroll
      for (int ni = 0; ni < 4; ++ni)
        acc[mi][ni] = __builtin_amdgcn_mfma_f32_16x16x32_bf16(af[mi], bfr[ni], acc[mi][ni], 0, 0, 0);
    __syncthreads();
  }
#pragma unroll
  for (int mi = 0; mi < 4; ++mi)
#pragma unroll
    for (int ni = 0; ni < 4; ++ni) {
      int col = n0 + wn * 64 + ni * 16 + lr;
      float bv = (!OUT_BF16 && bias) ? bias[col] : 0.f;
#pragma unroll
      for (int rr = 0; rr < 4; ++rr) {
        int row = m0 + wm * 64 + mi * 16 + lg * 4 + rr;
        if (OUT_BF16)
          ((unsigned short*)Cout)[(size_t)row * N + col] = b16(acc[mi][ni][rr]);
        else
          ((float*)Cout)[(size_t)row * N + col] = acc[mi][ni][rr] + bv;
      }
    }
}

// ---------------- RMSNorm(cols 0:512 -> cq, 512:1024 -> ckv) + RoPE k_rot (cols 1024:2048 -> K) --
__global__ __launch_bounds__(256) void rmsnorm_rope(const unsigned short* __restrict__ T1,
                                                    const float* __restrict__ gq,
                                                    const float* __restrict__ gkv,
                                                    unsigned short* __restrict__ cq,
                                                    unsigned short* __restrict__ ckv,
                                                    unsigned short* __restrict__ Kb) {
  const int row = blockIdx.x;
  const int t = threadIdx.x;
  const int s = row & 2047;
  const unsigned short* rp = T1 + (size_t)row * 2048;
  float xq0 = bf2f(rp[t]), xq1 = bf2f(rp[256 + t]);
  float xk0 = bf2f(rp[512 + t]), xk1 = bf2f(rp[768 + t]);
  float sq = xq0 * xq0 + xq1 * xq1;
  float sk = xk0 * xk0 + xk1 * xk1;
#pragma unroll
  for (int o = 1; o < 64; o <<= 1) { sq += __shfl_xor(sq, o); sk += __shfl_xor(sk, o); }
  __shared__ float red[8];
  if ((t & 63) == 0) { red[t >> 6] = sq; red[4 + (t >> 6)] = sk; }
  __syncthreads();
  float rq = rsqrtf((red[0] + red[1] + red[2] + red[3]) * (1.f / 512.f) + 1e-5f);
  float rk = rsqrtf((red[4] + red[5] + red[6] + red[7]) * (1.f / 512.f) + 1e-5f);
  cq[(size_t)row * 512 + t]        = b16(gq[t] * xq0 * rq);
  cq[(size_t)row * 512 + 256 + t]  = b16(gq[256 + t] * xq1 * rq);
  ckv[(size_t)row * 512 + t]       = b16(gkv[t] * xk0 * rk);
  ckv[(size_t)row * 512 + 256 + t] = b16(gkv[256 + t] * xk1 * rk);
#pragma unroll
  for (int i = 0; i < 4; ++i) {
    int j = t + 256 * i;                 // 0..1023
    int hh = j >> 6, d = j & 63;
    float ang = (float)s * __expf(-(float)(d & 31) * 0.14391156831f); // ln(10000)/64
    float sn, cs; __sincosf(ang, &sn, &cs);
    Kb[(size_t)row * 2048 + hh * 128 + 64 + d] = b16(bf2f(rp[1024 + j]) * (cs + sn));
  }
}

// ---------------- scatter GEMM2 output (bf16) into Q (with RoPE on rot half) ----------------
__global__ __launch_bounds__(256) void scatter_q(const unsigned short* __restrict__ T2,
                                                 unsigned short* __restrict__ Qb) {
  size_t idx = (size_t)blockIdx.x * 256 + threadIdx.x;  // 8M
  int row = (int)(idx >> 11);
  int col = (int)(idx & 2047);
  int hh = col >> 7, e = col & 127;
  unsigned short v;
  if (e < 64) {
    v = T2[(size_t)row * 2048 + hh * 64 + e];            // passthrough, no re-round
  } else {
    int d = e - 64;
    int s = row & 2047;
    float ang = (float)s * __expf(-(float)(d & 31) * 0.14391156831f);
    float sn, cs; __sincosf(ang, &sn, &cs);
    v = b16(bf2f(T2[(size_t)row * 2048 + 1024 + hh * 64 + d]) * (cs + sn));
  }
  Qb[idx] = v;
}

// ---------------- scatter GEMM3 k_base cols (bf16) into K ----------------
__global__ __launch_bounds__(256) void scatter_kbase(const unsigned short* __restrict__ T3,
                                                     unsigned short* __restrict__ Kb) {
  size_t idx = (size_t)blockIdx.x * 256 + threadIdx.x;  // 4M
  int row = (int)(idx >> 10);
  int col = (int)(idx & 1023);
  int hh = col >> 6, d = col & 63;
  Kb[(size_t)row * 2048 + hh * 128 + d] = T3[(size_t)row * 3072 + col];
}

// ---------------- causal flash attention ----------------
// round-2 structure (4 waves, QBLK=64, KV tiles 64) + T14 async-stage split
// + T13 defer-max + T5 setprio.
__global__ __launch_bounds__(256) void flash_attn(const unsigned short* __restrict__ Qb,
                                                  const unsigned short* __restrict__ Kb,
                                                  const unsigned short* __restrict__ VTb,
                                                  unsigned short* __restrict__ Ob) {
  __shared__ unsigned short Ks[64 * 128];
  __shared__ unsigned short Vs[128 * 64];
  __shared__ unsigned short Ps[4 * 16 * 72];
  const int b = blockIdx.z, h = blockIdx.y;
  const int q0 = blockIdx.x * 64;
  const int tid = threadIdx.x;
  const int w = tid >> 6, l = tid & 63;
  const int lg = l >> 4, lr = l & 15;
  const int qw0 = q0 + w * 16;
  const float scale = 0.0883883476483184f;   // 1/sqrt(128)

  v8bf qf[4];
  {
    const unsigned short* qp = Qb + (size_t)(b * 2048 + qw0 + lr) * 2048 + h * 128 + lg * 8;
#pragma unroll
    for (int ds = 0; ds < 4; ++ds) qf[ds] = *(const v8bf*)(qp + ds * 32);
  }
  v4f oacc[8];
#pragma unroll
  for (int i = 0; i < 8; ++i) oacc[i] = (v4f){0, 0, 0, 0};
  float mrow[4] = {-1e30f, -1e30f, -1e30f, -1e30f};
  float lsum[4] = {0, 0, 0, 0};

  const unsigned short* Kbase = Kb + (size_t)b * 2048 * 2048 + h * 128;
  const unsigned short* Vbase = VTb + (size_t)(b * 16 + h) * 128 * 2048;

  // T14: stage tile kv0 into regs (issue-early), write to LDS late.
  v4f kreg[4], vreg[4];
#pragma unroll
  for (int i = 0; i < 4; ++i) {
    int c = tid + 256 * i;
    kreg[i] = *(const v4f*)(Kbase + (size_t)(c >> 4) * 2048 + (c & 15) * 8);
  }
#pragma unroll
  for (int i = 0; i < 4; ++i) {
    int c = tid + 256 * i;
    vreg[i] = *(const v4f*)(Vbase + (size_t)(c >> 3) * 2048 + (c & 7) * 8);
  }

  const int nkv = q0 + 64;
  for (int kv0 = 0; kv0 < nkv; kv0 += 64) {
    // write staged regs -> LDS (XOR-swizzled)
#pragma unroll
    for (int i = 0; i < 4; ++i) {
      int c = tid + 256 * i;
      int r = c >> 4, dbl = c & 15;
      int off = (r * 256 + dbl * 16) ^ ((r & 7) << 4);
      *(v4f*)((char*)Ks + off) = kreg[i];
    }
#pragma unroll
    for (int i = 0; i < 4; ++i) {
      int c = tid + 256 * i;
      int d = c >> 3, kbl = c & 7;
      int off = (d * 128 + kbl * 16) ^ ((d & 7) << 4);
      *(v4f*)((char*)Vs + off) = vreg[i];
    }
    __syncthreads();
    // T14: issue next tile's global loads now; they land during compute.
    if (kv0 + 64 < nkv) {
      int kvn = kv0 + 64;
#pragma unroll
      for (int i = 0; i < 4; ++i) {
        int c = tid + 256 * i;
        kreg[i] = *(const v4f*)(Kbase + (size_t)(kvn + (c >> 4)) * 2048 + (c & 15) * 8);
      }
#pragma unroll
      for (int i = 0; i < 4; ++i) {
        int c = tid + 256 * i;
        vreg[i] = *(const v4f*)(Vbase + (size_t)(c >> 3) * 2048 + kvn + (c & 7) * 8);
      }
    }
    {
      float st[4][4];
      __builtin_amdgcn_s_setprio(1);
#pragma unroll
      for (int kt = 0; kt < 4; ++kt) {
        v4f sacc = (v4f){0, 0, 0, 0};
        int krow = kt * 16 + lr;
#pragma unroll
        for (int ds = 0; ds < 4; ++ds) {
          int off = (krow * 256 + ds * 64 + lg * 16) ^ ((krow & 7) << 4);
          v8bf kfr = *(const v8bf*)((char*)Ks + off);
          sacc = __builtin_amdgcn_mfma_f32_16x16x32_bf16(qf[ds], kfr, sacc, 0, 0, 0);
        }
        int colk = kv0 + kt * 16 + lr;
#pragma unroll
        for (int r = 0; r < 4; ++r) {
          int qrow = qw0 + lg * 4 + r;
          st[kt][r] = (colk <= qrow) ? sacc[r] * scale : -1e30f;
        }
      }
      __builtin_amdgcn_s_setprio(0);
#pragma unroll
      for (int r = 0; r < 4; ++r) {
        float mx = fmaxf(fmaxf(st[0][r], st[1][r]), fmaxf(st[2][r], st[3][r]));
#pragma unroll
        for (int o = 1; o < 16; o <<= 1) mx = fmaxf(mx, __shfl_xor(mx, o));
        // T13 defer-max: rescale only when tile max grew past mrow+8
        if (!__all(mx <= mrow[r] + 8.f)) {
          float mnew = fmaxf(mrow[r], mx);
          float sc = __expf(mrow[r] - mnew);
          lsum[r] *= sc;
#pragma unroll
          for (int dt = 0; dt < 8; ++dt) oacc[dt][r] *= sc;
          mrow[r] = mnew;
        }
        float ps = 0.f;
#pragma unroll
        for (int kt = 0; kt < 4; ++kt) {
          float p = __expf(st[kt][r] - mrow[r]);
          ps += p;
          Ps[w * 1152 + (lg * 4 + r) * 72 + kt * 16 + lr] = b16(p);
        }
        lsum[r] += ps;                 // per-lane partial (reduced in epilogue)
      }
      __builtin_amdgcn_s_setprio(1);
#pragma unroll
      for (int kh = 0; kh < 2; ++kh) {
        v8bf pa = *(const v8bf*)((char*)Ps + w * 2304 + lr * 144 + kh * 64 + lg * 16);
#pragma unroll
        for (int dt = 0; dt < 8; ++dt) {
          int d = dt * 16 + lr;
          int off = (d * 128 + kh * 64 + lg * 16) ^ ((d & 7) << 4);
          v8bf vfr = *(const v8bf*)((char*)Vs + off);
          oacc[dt] = __builtin_amdgcn_mfma_f32_16x16x32_bf16(pa, vfr, oacc[dt], 0, 0, 0);
        }
      }
      __builtin_amdgcn_s_setprio(0);
    }
    __syncthreads();
  }
#pragma unroll
  for (int r = 0; r < 4; ++r) {
    // lsum is a per-lane partial over this lane's 4 columns; reduce across
    // the 16-lane group to get the true row denominator.
    float ls = lsum[r];
#pragma unroll
    for (int o = 1; o < 16; o <<= 1) ls += __shfl_xor(ls, o);
    float inv = 1.f / ls;
    size_t orow = (size_t)(b * 2048 + qw0 + lg * 4 + r) * 2048 + h * 128;
#pragma unroll
    for (int dt = 0; dt < 8; ++dt)
      Ob[orow + dt * 16 + lr] = b16(oacc[dt][r] * inv);
  }
}

extern "C" void kernel_launch(void* const* d_in, const int* in_sizes, int n_in,
                              void* d_out, int out_size, void* d_ws, size_t ws_size,
                              hipStream_t stream) {
  const float* x    = (const float*)d_in[0];
  const float* Wdq  = (const float*)d_in[1];
  const float* Wuq  = (const float*)d_in[2];
  const float* Wdkv = (const float*)d_in[3];
  const float* Wuk  = (const float*)d_in[4];
  const float* Wuv  = (const float*)d_in[5];
  const float* Wqr  = (const float*)d_in[6];
  const float* Wkr  = (const float*)d_in[7];
  const float* gq   = (const float*)d_in[8];
  const float* gkv  = (const float*)d_in[9];
  const float* Wout = (const float*)d_in[10];
  const float* bout = (const float*)d_in[11];
  float* out = (float*)d_out;

  // ---- workspace layout (bf16 elems), ~69MB total ----
  const size_t M1 = 1024 * 1024;
  unsigned short* xb  = (unsigned short*)d_ws;   // [0,8M)   xb; later Qb
  unsigned short* Qb  = xb;
  unsigned short* T   = xb + 8 * M1;             // [8M,20M) T1/T2/T3 (bf16); later Ob
  unsigned short* Ob  = T;
  unsigned short* W1T = xb + 20 * M1;            // 4M   [2048][2048]
  unsigned short* W2T = xb + 24 * M1;            // 1M   [2048][512]
  unsigned short* W3T = xb + 25 * M1;            // 1.5M [3072][512]
  unsigned short* WoT = W3T + 1536 * 1024;       // 4M   [2048][2048]
  unsigned short* cq  = xb + 30 * M1 + 512 * 1024; // 2M
  unsigned short* ckv = cq + 2 * M1;             // 2M   (ends at 34.5M elems = 69MB)
  // ---- K and V^T live in d_out (32MB of its 33.5MB), dead before GEMM4 overwrites ----
  unsigned short* Kb = (unsigned short*)d_out;   // 8M elems [b][s][h*128+d]
  unsigned short* VT = Kb + 8 * M1;              // 8M elems [bh][d][s]

  dim3 b256(256), tb(32, 8);

  conv_bf16<<<8192, b256, 0, stream>>>(x, xb);
  transpose_w<<<dim3(16, 64), tb, 0, stream>>>(Wdq,  W1T,                       512, 2048);
  transpose_w<<<dim3(16, 64), tb, 0, stream>>>(Wdkv, W1T + (size_t)512 * 2048,  512, 2048);
  transpose_w<<<dim3(32, 64), tb, 0, stream>>>(Wkr,  W1T + (size_t)1024 * 2048, 1024, 2048);
  transpose_w<<<dim3(32, 16), tb, 0, stream>>>(Wuq,  W2T,                       1024, 512);
  transpose_w<<<dim3(32, 16), tb, 0, stream>>>(Wqr,  W2T + (size_t)1024 * 512,  1024, 512);
  transpose_w<<<dim3(32, 16), tb, 0, stream>>>(Wuk,  W3T,                       1024, 512);
  transpose_w<<<dim3(64, 16), tb, 0, stream>>>(Wuv,  W3T + (size_t)1024 * 512,  2048, 512);
  transpose_w<<<dim3(64, 64), tb, 0, stream>>>(Wout, WoT,                       2048, 2048);

  // GEMM1: x @ [W_dq | W_dkv | W_kr] -> T1 (bf16)
  gemm_bt<true><<<dim3(16, 32), b256, 0, stream>>>(xb, W1T, T, nullptr, 4096, 2048, 2048);
  rmsnorm_rope<<<4096, b256, 0, stream>>>(T, gq, gkv, cq, ckv, Kb);
  // GEMM2: c_q @ [W_uq | W_qr] -> T2 (bf16)
  gemm_bt<true><<<dim3(16, 32), b256, 0, stream>>>(cq, W2T, T, nullptr, 4096, 2048, 512);
  scatter_q<<<32768, b256, 0, stream>>>(T, Qb);           // xb dead: Qb aliases it
  // GEMM3: c_kv @ [W_uk | W_uv] -> T3 (bf16)
  gemm_bt<true><<<dim3(24, 32), b256, 0, stream>>>(ckv, W3T, T, nullptr, 4096, 3072, 512);
  scatter_kbase<<<16384, b256, 0, stream>>>(T, Kb);
  transpose_v<<<dim3(64, 4, 32), tb, 0, stream>>>(T, VT);

  flash_attn<<<dim3(32, 16, 2), b256, 0, stream>>>(Qb, Kb, VT, Ob);  // T3 dead: Ob aliases T

  // GEMM4: O @ W_out + b_out -> out (fp32); Kb/VT in d_out are dead now
  gemm_bt<false><<<dim3(16, 32), b256, 0, stream>>>(Ob, WoT, out, bout, 4096, 2048, 2048);
}

// Round 5
// 309.849 us; speedup vs baseline: 1.6233x; 1.6233x over previous
//
#include <hip/hip_runtime.h>
#include <hip/hip_bf16.h>
#include <cstdint>

typedef __bf16 v8bf __attribute__((ext_vector_type(8)));
typedef float  v4f  __attribute__((ext_vector_type(4)));

__device__ __forceinline__ unsigned short b16(float f) {
  union { float f; unsigned u; } v; v.f = f;
  unsigned u = v.u;
  return (unsigned short)((u + 0x7fffu + ((u >> 16) & 1u)) >> 16);
}
__device__ __forceinline__ float bf2f(unsigned short u) {
  union { unsigned u; float f; } v; v.u = ((unsigned)u) << 16; return v.f;
}

#define GLOAD_LDS16(g, l)                                                     \
  __builtin_amdgcn_global_load_lds(                                           \
      (const __attribute__((address_space(1))) void*)(g),                     \
      (__attribute__((address_space(3))) void*)(l), 16, 0, 0)

// ---------------- elementwise fp32 -> bf16 convert (x) ----------------
__global__ __launch_bounds__(256) void conv_bf16(const float* __restrict__ in,
                                                 unsigned short* __restrict__ out) {
  size_t idx = (size_t)blockIdx.x * 256 + threadIdx.x;   // one thread = 4 elems
  v4f v = *(const v4f*)(in + idx * 4);
  unsigned long long p = (unsigned long long)b16(v[0]) |
                         ((unsigned long long)b16(v[1]) << 16) |
                         ((unsigned long long)b16(v[2]) << 32) |
                         ((unsigned long long)b16(v[3]) << 48);
  *(unsigned long long*)(out + idx * 4) = p;
}

// ---------------- weight transpose: in[R][C] fp32 -> out[c*R + r] bf16 ----------------
__global__ void transpose_w(const float* __restrict__ in, unsigned short* __restrict__ out,
                            int C, int R) {
  __shared__ float tile[32][33];
  int c0 = blockIdx.x * 32, r0 = blockIdx.y * 32;
  int x = threadIdx.x, y = threadIdx.y;
#pragma unroll
  for (int i = 0; i < 4; ++i)
    tile[y + 8 * i][x] = in[(size_t)(r0 + y + 8 * i) * C + c0 + x];
  __syncthreads();
#pragma unroll
  for (int i = 0; i < 4; ++i)
    out[(size_t)(c0 + y + 8 * i) * R + r0 + x] = b16(tile[x][y + 8 * i]);
}

// ---------------- V transpose: T3[row][1024 + h*128 + d] (bf16) -> VT[bh][d][s] bf16 ----------------
__global__ void transpose_v(const unsigned short* __restrict__ T3, unsigned short* __restrict__ VT) {
  __shared__ unsigned short tile[32][34];
  int bh = blockIdx.z;
  int s0 = blockIdx.x * 32, d0 = blockIdx.y * 32;
  int x = threadIdx.x, y = threadIdx.y;
  const unsigned short* src = T3 + (size_t)(bh >> 4) * 2048 * 3072 + 1024 + (bh & 15) * 128;
#pragma unroll
  for (int i = 0; i < 4; ++i)
    tile[y + 8 * i][x] = src[(size_t)(s0 + y + 8 * i) * 3072 + d0 + x];
  __syncthreads();
  unsigned short* dst = VT + (size_t)bh * 128 * 2048;
#pragma unroll
  for (int i = 0; i < 4; ++i)
    dst[(size_t)(d0 + y + 8 * i) * 2048 + s0 + x] = tile[x][y + 8 * i];
}

// ---------------- GEMM: C[M,N] = A[M,K](bf16) * BT[N,K](bf16) ----------------
// m97 recipe: 128x128 tile, BK=32, 4 waves (2x2), global_load_lds width=16
// into LINEAR [128][32] LDS (wave-uniform base + lane*16 — no padding allowed).
template <bool OUT_BF16>
__global__ __launch_bounds__(256) void gemm_bt(const unsigned short* __restrict__ A,
                                               const unsigned short* __restrict__ BT,
                                               void* __restrict__ Cout,
                                               const float* __restrict__ bias,
                                               int M, int N, int K) {
  __shared__ unsigned short As[128 * 32];
  __shared__ unsigned short Bs[128 * 32];
  const int tid = threadIdx.x;
  const int w = tid >> 6, l = tid & 63;
  const int wm = w >> 1, wn = w & 1;
  const int lg = l >> 4, lr = l & 15;
  const int m0 = blockIdx.y * 128, n0 = blockIdx.x * 128;

  // staging map: call i covers tile rows i*64 + tid/4, k-chunk (tid&3)*8
  const int srow = tid >> 2, scol = (tid & 3) * 8;
  const unsigned short* Ap0 = A  + (size_t)(m0 + srow) * K + scol;
  const unsigned short* Ap1 = A  + (size_t)(m0 + 64 + srow) * K + scol;
  const unsigned short* Bp0 = BT + (size_t)(n0 + srow) * K + scol;
  const unsigned short* Bp1 = BT + (size_t)(n0 + 64 + srow) * K + scol;
  unsigned short* Ad0 = As + tid * 8;          // byte tid*16
  unsigned short* Ad1 = As + 2048 + tid * 8;   // byte 4096 + tid*16
  unsigned short* Bd0 = Bs + tid * 8;
  unsigned short* Bd1 = Bs + 2048 + tid * 8;

  v4f acc[4][4];
#pragma unroll
  for (int i = 0; i < 4; ++i)
#pragma unroll
    for (int j = 0; j < 4; ++j) acc[i][j] = (v4f){0.f, 0.f, 0.f, 0.f};

  for (int k0 = 0; k0 < K; k0 += 32) {
    GLOAD_LDS16(Ap0 + k0, Ad0);
    GLOAD_LDS16(Ap1 + k0, Ad1);
    GLOAD_LDS16(Bp0 + k0, Bd0);
    GLOAD_LDS16(Bp1 + k0, Bd1);
    __syncthreads();
    v8bf af[4], bfr[4];
#pragma unroll
    for (int mi = 0; mi < 4; ++mi)
      af[mi] = *(const v8bf*)&As[(wm * 64 + mi * 16 + lr) * 32 + lg * 8];
#pragma unroll
    for (int ni = 0; ni < 4; ++ni)
      bfr[ni] = *(const v8bf*)&Bs[(wn * 64 + ni * 16 + lr) * 32 + lg * 8];
#pragma unroll
    for (int mi = 0; mi < 4; ++mi)
#pragma unroll
      for (int ni = 0; ni < 4; ++ni)
        acc[mi][ni] = __builtin_amdgcn_mfma_f32_16x16x32_bf16(af[mi], bfr[ni], acc[mi][ni], 0, 0, 0);
    __syncthreads();
  }
#pragma unroll
  for (int mi = 0; mi < 4; ++mi)
#pragma unroll
    for (int ni = 0; ni < 4; ++ni) {
      int col = n0 + wn * 64 + ni * 16 + lr;
      float bv = (!OUT_BF16 && bias) ? bias[col] : 0.f;
#pragma unroll
      for (int rr = 0; rr < 4; ++rr) {
        int row = m0 + wm * 64 + mi * 16 + lg * 4 + rr;
        if (OUT_BF16)
          ((unsigned short*)Cout)[(size_t)row * N + col] = b16(acc[mi][ni][rr]);
        else
          ((float*)Cout)[(size_t)row * N + col] = acc[mi][ni][rr] + bv;
      }
    }
}

// ---------------- RMSNorm(cols 0:512 -> cq, 512:1024 -> ckv) + RoPE k_rot (cols 1024:2048 -> K) --
__global__ __launch_bounds__(256) void rmsnorm_rope(const unsigned short* __restrict__ T1,
                                                    const float* __restrict__ gq,
                                                    const float* __restrict__ gkv,
                                                    unsigned short* __restrict__ cq,
                                                    unsigned short* __restrict__ ckv,
                                                    unsigned short* __restrict__ Kb) {
  const int row = blockIdx.x;
  const int t = threadIdx.x;
  const int s = row & 2047;
  const unsigned short* rp = T1 + (size_t)row * 2048;
  float xq0 = bf2f(rp[t]), xq1 = bf2f(rp[256 + t]);
  float xk0 = bf2f(rp[512 + t]), xk1 = bf2f(rp[768 + t]);
  float sq = xq0 * xq0 + xq1 * xq1;
  float sk = xk0 * xk0 + xk1 * xk1;
#pragma unroll
  for (int o = 1; o < 64; o <<= 1) { sq += __shfl_xor(sq, o); sk += __shfl_xor(sk, o); }
  __shared__ float red[8];
  if ((t & 63) == 0) { red[t >> 6] = sq; red[4 + (t >> 6)] = sk; }
  __syncthreads();
  float rq = rsqrtf((red[0] + red[1] + red[2] + red[3]) * (1.f / 512.f) + 1e-5f);
  float rk = rsqrtf((red[4] + red[5] + red[6] + red[7]) * (1.f / 512.f) + 1e-5f);
  cq[(size_t)row * 512 + t]        = b16(gq[t] * xq0 * rq);
  cq[(size_t)row * 512 + 256 + t]  = b16(gq[256 + t] * xq1 * rq);
  ckv[(size_t)row * 512 + t]       = b16(gkv[t] * xk0 * rk);
  ckv[(size_t)row * 512 + 256 + t] = b16(gkv[256 + t] * xk1 * rk);
#pragma unroll
  for (int i = 0; i < 4; ++i) {
    int j = t + 256 * i;                 // 0..1023
    int hh = j >> 6, d = j & 63;
    float ang = (float)s * __expf(-(float)(d & 31) * 0.14391156831f); // ln(10000)/64
    float sn, cs; __sincosf(ang, &sn, &cs);
    Kb[(size_t)row * 2048 + hh * 128 + 64 + d] = b16(bf2f(rp[1024 + j]) * (cs + sn));
  }
}

// ---------------- scatter GEMM2 output (bf16) into Q (with RoPE on rot half) ----------------
__global__ __launch_bounds__(256) void scatter_q(const unsigned short* __restrict__ T2,
                                                 unsigned short* __restrict__ Qb) {
  size_t idx = (size_t)blockIdx.x * 256 + threadIdx.x;  // 8M
  int row = (int)(idx >> 11);
  int col = (int)(idx & 2047);
  int hh = col >> 7, e = col & 127;
  unsigned short v;
  if (e < 64) {
    v = T2[(size_t)row * 2048 + hh * 64 + e];            // passthrough, no re-round
  } else {
    int d = e - 64;
    int s = row & 2047;
    float ang = (float)s * __expf(-(float)(d & 31) * 0.14391156831f);
    float sn, cs; __sincosf(ang, &sn, &cs);
    v = b16(bf2f(T2[(size_t)row * 2048 + 1024 + hh * 64 + d]) * (cs + sn));
  }
  Qb[idx] = v;
}

// ---------------- scatter GEMM3 k_base cols (bf16) into K ----------------
__global__ __launch_bounds__(256) void scatter_kbase(const unsigned short* __restrict__ T3,
                                                     unsigned short* __restrict__ Kb) {
  size_t idx = (size_t)blockIdx.x * 256 + threadIdx.x;  // 4M
  int row = (int)(idx >> 10);
  int col = (int)(idx & 1023);
  int hh = col >> 6, d = col & 63;
  Kb[(size_t)row * 2048 + hh * 128 + d] = T3[(size_t)row * 3072 + col];
}

// ---------------- causal flash attention (round-2 structure + qblock PAIRING) ----------------
// grid (16 pairs, 16 h, 2 b), 4 waves; wave = 16 q rows; KV tiles of 64.
// CTA bx processes qblocks {bx, 31-bx}: (bx+1) + (32-bx) = 33 tiles each ->
// perfectly balanced causal work, 512 CTAs = exactly 2/CU, all resident.
__global__ __launch_bounds__(256) void flash_attn(const unsigned short* __restrict__ Qb,
                                                  const unsigned short* __restrict__ Kb,
                                                  const unsigned short* __restrict__ VTb,
                                                  unsigned short* __restrict__ Ob) {
  __shared__ unsigned short Ks[64 * 128];
  __shared__ unsigned short Vs[128 * 64];
  __shared__ unsigned short Ps[4 * 16 * 72];
  const int b = blockIdx.z, h = blockIdx.y;
  const int tid = threadIdx.x;
  const int w = tid >> 6, l = tid & 63;
  const int lg = l >> 4, lr = l & 15;
  const float scale = 0.0883883476483184f;   // 1/sqrt(128)

  const unsigned short* Kbase = Kb + (size_t)b * 2048 * 2048 + h * 128;
  const unsigned short* Vbase = VTb + (size_t)(b * 16 + h) * 128 * 2048;

  for (int pass = 0; pass < 2; ++pass) {
    const int q0 = (pass ? (31 - blockIdx.x) : blockIdx.x) * 64;
    const int qw0 = q0 + w * 16;

    v8bf qf[4];
    {
      const unsigned short* qp = Qb + (size_t)(b * 2048 + qw0 + lr) * 2048 + h * 128 + lg * 8;
#pragma unroll
      for (int ds = 0; ds < 4; ++ds) qf[ds] = *(const v8bf*)(qp + ds * 32);
    }
    v4f oacc[8];
#pragma unroll
    for (int i = 0; i < 8; ++i) oacc[i] = (v4f){0, 0, 0, 0};
    float mrow[4] = {-1e30f, -1e30f, -1e30f, -1e30f};
    float lsum[4] = {0, 0, 0, 0};

    const int nkv = q0 + 64;
    for (int kv0 = 0; kv0 < nkv; kv0 += 64) {
#pragma unroll
      for (int i = 0; i < 4; ++i) {         // stage K tile [64][128]
        int c = tid + 256 * i;
        int r = c >> 4, dbl = c & 15;
        int off = (r * 256 + dbl * 16) ^ ((r & 7) << 4);
        *(v4f*)((char*)Ks + off) =
            *(const v4f*)(Kbase + (size_t)(kv0 + r) * 2048 + dbl * 8);
      }
#pragma unroll
      for (int i = 0; i < 4; ++i) {         // stage V tile [128 d][64 k]
        int c = tid + 256 * i;
        int d = c >> 3, kbl = c & 7;
        int off = (d * 128 + kbl * 16) ^ ((d & 7) << 4);
        *(v4f*)((char*)Vs + off) =
            *(const v4f*)(Vbase + (size_t)d * 2048 + kv0 + kbl * 8);
      }
      __syncthreads();
      {
        float st[4][4];
#pragma unroll
        for (int kt = 0; kt < 4; ++kt) {
          v4f sacc = (v4f){0, 0, 0, 0};
          int krow = kt * 16 + lr;
#pragma unroll
          for (int ds = 0; ds < 4; ++ds) {
            int off = (krow * 256 + ds * 64 + lg * 16) ^ ((krow & 7) << 4);
            v8bf kfr = *(const v8bf*)((char*)Ks + off);
            sacc = __builtin_amdgcn_mfma_f32_16x16x32_bf16(qf[ds], kfr, sacc, 0, 0, 0);
          }
          int colk = kv0 + kt * 16 + lr;
#pragma unroll
          for (int r = 0; r < 4; ++r) {
            int qrow = qw0 + lg * 4 + r;
            st[kt][r] = (colk <= qrow) ? sacc[r] * scale : -1e30f;
          }
        }
#pragma unroll
        for (int r = 0; r < 4; ++r) {
          float mx = fmaxf(fmaxf(st[0][r], st[1][r]), fmaxf(st[2][r], st[3][r]));
#pragma unroll
          for (int o = 1; o < 16; o <<= 1) mx = fmaxf(mx, __shfl_xor(mx, o));
          float mnew = fmaxf(mrow[r], mx);
          float sc = __expf(mrow[r] - mnew);
          float ps = 0.f;
#pragma unroll
          for (int kt = 0; kt < 4; ++kt) {
            float p = __expf(st[kt][r] - mnew);
            ps += p;
            Ps[w * 1152 + (lg * 4 + r) * 72 + kt * 16 + lr] = b16(p);
          }
          lsum[r] = lsum[r] * sc + ps;     // per-lane partial (reduced in epilogue)
          mrow[r] = mnew;
#pragma unroll
          for (int dt = 0; dt < 8; ++dt) oacc[dt][r] *= sc;
        }
#pragma unroll
        for (int kh = 0; kh < 2; ++kh) {
          v8bf pa = *(const v8bf*)((char*)Ps + w * 2304 + lr * 144 + kh * 64 + lg * 16);
#pragma unroll
          for (int dt = 0; dt < 8; ++dt) {
            int d = dt * 16 + lr;
            int off = (d * 128 + kh * 64 + lg * 16) ^ ((d & 7) << 4);
            v8bf vfr = *(const v8bf*)((char*)Vs + off);
            oacc[dt] = __builtin_amdgcn_mfma_f32_16x16x32_bf16(pa, vfr, oacc[dt], 0, 0, 0);
          }
        }
      }
      __syncthreads();
    }
#pragma unroll
    for (int r = 0; r < 4; ++r) {
      // lsum is a per-lane partial over this lane's 4 columns; reduce across
      // the 16-lane group to get the true row denominator.
      float ls = lsum[r];
#pragma unroll
      for (int o = 1; o < 16; o <<= 1) ls += __shfl_xor(ls, o);
      float inv = 1.f / ls;
      size_t orow = (size_t)(b * 2048 + qw0 + lg * 4 + r) * 2048 + h * 128;
#pragma unroll
      for (int dt = 0; dt < 8; ++dt)
        Ob[orow + dt * 16 + lr] = b16(oacc[dt][r] * inv);
    }
  }
}

extern "C" void kernel_launch(void* const* d_in, const int* in_sizes, int n_in,
                              void* d_out, int out_size, void* d_ws, size_t ws_size,
                              hipStream_t stream) {
  const float* x    = (const float*)d_in[0];
  const float* Wdq  = (const float*)d_in[1];
  const float* Wuq  = (const float*)d_in[2];
  const float* Wdkv = (const float*)d_in[3];
  const float* Wuk  = (const float*)d_in[4];
  const float* Wuv  = (const float*)d_in[5];
  const float* Wqr  = (const float*)d_in[6];
  const float* Wkr  = (const float*)d_in[7];
  const float* gq   = (const float*)d_in[8];
  const float* gkv  = (const float*)d_in[9];
  const float* Wout = (const float*)d_in[10];
  const float* bout = (const float*)d_in[11];
  float* out = (float*)d_out;

  // ---- workspace layout (bf16 elems), ~69MB total ----
  const size_t M1 = 1024 * 1024;
  unsigned short* xb  = (unsigned short*)d_ws;   // [0,8M)   xb; later Qb
  unsigned short* Qb  = xb;
  unsigned short* T   = xb + 8 * M1;             // [8M,20M) T1/T2/T3 (bf16); later Ob
  unsigned short* Ob  = T;
  unsigned short* W1T = xb + 20 * M1;            // 4M   [2048][2048]
  unsigned short* W2T = xb + 24 * M1;            // 1M   [2048][512]
  unsigned short* W3T = xb + 25 * M1;            // 1.5M [3072][512]
  unsigned short* WoT = W3T + 1536 * 1024;       // 4M   [2048][2048]
  unsigned short* cq  = xb + 30 * M1 + 512 * 1024; // 2M
  unsigned short* ckv = cq + 2 * M1;             // 2M   (ends at 34.5M elems = 69MB)
  // ---- K and V^T live in d_out (32MB of its 33.5MB), dead before GEMM4 overwrites ----
  unsigned short* Kb = (unsigned short*)d_out;   // 8M elems [b][s][h*128+d]
  unsigned short* VT = Kb + 8 * M1;              // 8M elems [bh][d][s]

  dim3 b256(256), tb(32, 8);

  conv_bf16<<<8192, b256, 0, stream>>>(x, xb);
  transpose_w<<<dim3(16, 64), tb, 0, stream>>>(Wdq,  W1T,                       512, 2048);
  transpose_w<<<dim3(16, 64), tb, 0, stream>>>(Wdkv, W1T + (size_t)512 * 2048,  512, 2048);
  transpose_w<<<dim3(32, 64), tb, 0, stream>>>(Wkr,  W1T + (size_t)1024 * 2048, 1024, 2048);
  transpose_w<<<dim3(32, 16), tb, 0, stream>>>(Wuq,  W2T,                       1024, 512);
  transpose_w<<<dim3(32, 16), tb, 0, stream>>>(Wqr,  W2T + (size_t)1024 * 512,  1024, 512);
  transpose_w<<<dim3(32, 16), tb, 0, stream>>>(Wuk,  W3T,                       1024, 512);
  transpose_w<<<dim3(64, 16), tb, 0, stream>>>(Wuv,  W3T + (size_t)1024 * 512,  2048, 512);
  transpose_w<<<dim3(64, 64), tb, 0, stream>>>(Wout, WoT,                       2048, 2048);

  // GEMM1: x @ [W_dq | W_dkv | W_kr] -> T1 (bf16)
  gemm_bt<true><<<dim3(16, 32), b256, 0, stream>>>(xb, W1T, T, nullptr, 4096, 2048, 2048);
  rmsnorm_rope<<<4096, b256, 0, stream>>>(T, gq, gkv, cq, ckv, Kb);
  // GEMM2: c_q @ [W_uq | W_qr] -> T2 (bf16)
  gemm_bt<true><<<dim3(16, 32), b256, 0, stream>>>(cq, W2T, T, nullptr, 4096, 2048, 512);
  scatter_q<<<32768, b256, 0, stream>>>(T, Qb);           // xb dead: Qb aliases it
  // GEMM3: c_kv @ [W_uk | W_uv] -> T3 (bf16)
  gemm_bt<true><<<dim3(24, 32), b256, 0, stream>>>(ckv, W3T, T, nullptr, 4096, 3072, 512);
  scatter_kbase<<<16384, b256, 0, stream>>>(T, Kb);
  transpose_v<<<dim3(64, 4, 32), tb, 0, stream>>>(T, VT);

  flash_attn<<<dim3(16, 16, 2), b256, 0, stream>>>(Qb, Kb, VT, Ob);  // T3 dead: Ob aliases T

  // GEMM4: O @ W_out + b_out -> out (fp32); Kb/VT in d_out are dead now
  gemm_bt<false><<<dim3(16, 32), b256, 0, stream>>>(Ob, WoT, out, bout, 4096, 2048, 2048);
}